// Round 6
// baseline (207.207 us; speedup 1.0000x reference)
//
#include <hip/hip_runtime.h>

#define B_    2
#define N_    2048
#define EMBED 896
#define HQ    16
#define HK    4
#define D_    56
#define DP    64

typedef unsigned short u16;
typedef unsigned int   u32;
typedef __attribute__((ext_vector_type(8))) short bf16x8;
typedef __attribute__((ext_vector_type(4))) float f32x4;

__device__ __forceinline__ u16 f2bf(float f) {
  u32 u = __builtin_bit_cast(u32, f);
  return (u16)((u + 0x7FFFu + ((u >> 16) & 1u)) >> 16);
}

#define EXP2F(x) __builtin_amdgcn_exp2f(x)

// QSCALE = (1/sqrt(56)) * log2(e); folded into Q so softmax uses exp2
#define QSCALE 0.19278822f

// ---------------------------------------------------------------------------
// Bulk f32 -> bf16 conversion of q/k/v inputs and the four weights.
// ---------------------------------------------------------------------------
#define SEG_IN  3670016u   // 2*2048*896
#define SEG_WQ  802816u    // 896*896
#define SEG_WK  200704u    // 224*896

__global__ __launch_bounds__(256) void to_bf16(
    const float* __restrict__ q, const float* __restrict__ k,
    const float* __restrict__ v, const float* __restrict__ wq,
    const float* __restrict__ wk, const float* __restrict__ wv,
    const float* __restrict__ wo, u16* __restrict__ qb, u16* __restrict__ kb,
    u16* __restrict__ vb, u16* __restrict__ wqb, u16* __restrict__ wkb,
    u16* __restrict__ wvb, u16* __restrict__ wob) {
  size_t e = ((size_t)blockIdx.x * 256 + threadIdx.x) * 4;
  const float* src;
  u16* dst;
  size_t off;
  if (e < SEG_IN)            { src = q;  dst = qb;  off = e; }
  else if (e < 2 * (size_t)SEG_IN) { src = k;  dst = kb;  off = e - SEG_IN; }
  else if (e < 3 * (size_t)SEG_IN) { src = v;  dst = vb;  off = e - 2 * (size_t)SEG_IN; }
  else {
    size_t r = e - 3 * (size_t)SEG_IN;
    if (r < SEG_WQ)                    { src = wq; dst = wqb; off = r; }
    else if (r < SEG_WQ + SEG_WK)      { src = wk; dst = wkb; off = r - SEG_WQ; }
    else if (r < SEG_WQ + 2 * SEG_WK)  { src = wv; dst = wvb; off = r - SEG_WQ - SEG_WK; }
    else                               { src = wo; dst = wob; off = r - SEG_WQ - 2 * SEG_WK; }
  }
  float4 v4 = *(const float4*)(src + off);
  uint2 pb;
  pb.x = (u32)f2bf(v4.x) | ((u32)f2bf(v4.y) << 16);
  pb.y = (u32)f2bf(v4.z) | ((u32)f2bf(v4.w) << 16);
  *(uint2*)(dst + off) = pb;
}

// ---------------------------------------------------------------------------
// Fused QKV projection GEMM. BM=128, BN=64, BK=64; grid (32, 22).
// Double-buffered LDS + 3-deep (2-step in-flight) register prefetch:
// tile issued at step t is ds_written at step t+2 -> ~2 K-steps of latency
// cover. One barrier per K-step. V epilogue transposed for coalesced writes.
// ---------------------------------------------------------------------------
#define NT_K 14  // 896/64

__global__ __launch_bounds__(256) void proj_gemm(
    const u16* __restrict__ qb, const u16* __restrict__ kb,
    const u16* __restrict__ vb, const u16* __restrict__ Wqb,
    const u16* __restrict__ Wkb, const u16* __restrict__ Wvb,
    u16* __restrict__ Qp, u16* __restrict__ Kp, u16* __restrict__ Vt) {
  __shared__ __align__(16) u16 As[2][128][68];
  __shared__ __align__(16) u16 Bs[2][64][68];
  const int t = threadIdx.x;
  const int m0 = blockIdx.x * 128;
  const int y = blockIdx.y;
  int p, nt;
  if (y < 14)      { p = 0; nt = y; }
  else if (y < 18) { p = 1; nt = y - 14; }
  else             { p = 2; nt = y - 18; }
  const u16* A = p == 0 ? qb : (p == 1 ? kb : vb);
  const u16* W = p == 0 ? Wqb : (p == 1 ? Wkb : Wvb);
  const int Nproj = p == 0 ? 896 : 224;
  const int wn0 = nt * 64;

  const int w = t >> 6, lane = t & 63;
  const int fr = lane & 15, fg = lane >> 4;
  const int wr = w * 32;

  f32x4 acc[2][4] = {};
  int4 a0[4], b0[2], a1[4], b1[2];

#define PJ_LOAD(ar_, br_, k0_)                                                 \
  {                                                                            \
    _Pragma("unroll") for (int i = 0; i < 4; i++) {                            \
      int flat = i * 256 + t;                                                  \
      int r = flat >> 3, c = (flat & 7) * 8;                                   \
      ar_[i] = *(const int4*)(A + (size_t)(m0 + r) * EMBED + (k0_) + c);       \
    }                                                                          \
    _Pragma("unroll") for (int i = 0; i < 2; i++) {                            \
      int flat = i * 256 + t;                                                  \
      int r = flat >> 3, c = (flat & 7) * 8;                                   \
      int4 z = {0, 0, 0, 0};                                                   \
      if (wn0 + r < Nproj)                                                     \
        z = *(const int4*)(W + (size_t)(wn0 + r) * EMBED + (k0_) + c);         \
      br_[i] = z;                                                              \
    }                                                                          \
  }
#define PJ_WRITE(buf_, ar_, br_)                                               \
  {                                                                            \
    _Pragma("unroll") for (int i = 0; i < 4; i++) {                            \
      int flat = i * 256 + t;                                                  \
      *(int4*)&As[buf_][flat >> 3][(flat & 7) * 8] = ar_[i];                   \
    }                                                                          \
    _Pragma("unroll") for (int i = 0; i < 2; i++) {                            \
      int flat = i * 256 + t;                                                  \
      *(int4*)&Bs[buf_][flat >> 3][(flat & 7) * 8] = br_[i];                   \
    }                                                                          \
  }
#define PJ_COMPUTE(buf_)                                                       \
  {                                                                            \
    _Pragma("unroll") for (int kk = 0; kk < 2; kk++) {                         \
      bf16x8 af[2], bfv[4];                                                    \
      _Pragma("unroll") for (int mf = 0; mf < 2; mf++)                         \
          af[mf] =                                                             \
          *(const bf16x8*)&As[buf_][wr + mf * 16 + fr][kk * 32 + fg * 8];      \
      _Pragma("unroll") for (int nf = 0; nf < 4; nf++)                         \
          bfv[nf] = *(const bf16x8*)&Bs[buf_][nf * 16 + fr][kk * 32 + fg * 8]; \
      _Pragma("unroll") for (int mf = 0; mf < 2; mf++)                         \
          _Pragma("unroll") for (int nf = 0; nf < 4; nf++)                     \
              acc[mf][nf] = __builtin_amdgcn_mfma_f32_16x16x32_bf16(           \
                  af[mf], bfv[nf], acc[mf][nf], 0, 0, 0);                      \
    }                                                                          \
  }

  // prologue: tiles 0,1 -> regs; tile0 -> buf0; tile2 -> regs(set0)
  PJ_LOAD(a0, b0, 0);
  PJ_LOAD(a1, b1, 64);
  PJ_WRITE(0, a0, b0);
  PJ_LOAD(a0, b0, 128);
  __syncthreads();

#pragma unroll
  for (int it = 0; it < NT_K; it += 2) {
    // even step: compute tile it (buf0); stage tile it+1 (set1); issue it+3
    PJ_WRITE(1, a1, b1);
    if (it + 3 < NT_K) PJ_LOAD(a1, b1, (it + 3) * 64);
    PJ_COMPUTE(0);
    __syncthreads();
    // odd step: compute tile it+1 (buf1); stage tile it+2 (set0); issue it+4
    if (it + 2 < NT_K) PJ_WRITE(0, a0, b0);
    if (it + 4 < NT_K) PJ_LOAD(a0, b0, (it + 4) * 64);
    PJ_COMPUTE(1);
    __syncthreads();
  }

  if (p < 2) {
#pragma unroll
    for (int nf = 0; nf < 4; nf++) {
      int col = wn0 + nf * 16 + fr;
      if (col < Nproj) {
        int hh = col / 56, d = col - hh * 56;
#pragma unroll
        for (int mf = 0; mf < 2; mf++)
#pragma unroll
          for (int r = 0; r < 4; r++) {
            int row = m0 + wr + mf * 16 + fg * 4 + r;
            int bb = row >> 11, nn = row & 2047;
            float vv = acc[mf][nf][r];
            if (p == 0)
              Qp[((size_t)((bb * 16 + hh) * 2048 + nn)) * 64 + d] =
                  f2bf(vv * QSCALE);
            else
              Kp[((size_t)((bb * 4 + hh) * 2048 + nn)) * 64 + d] = f2bf(vv);
          }
      }
    }
  } else {
    // V: transpose through LDS, then coalesced 256B-contiguous stores
    u16* Traw = &As[0][0][0];  // reuse; need 64*136 = 8704 u16
#define TS(r_, c_) Traw[(r_)*136 + (c_)]
#pragma unroll
    for (int nf = 0; nf < 4; nf++)
#pragma unroll
      for (int mf = 0; mf < 2; mf++)
#pragma unroll
        for (int r = 0; r < 4; r++)
          TS(nf * 16 + fr, wr + mf * 16 + fg * 4 + r) = f2bf(acc[mf][nf][r]);
    __syncthreads();
    const int bb = m0 >> 11, n_base = m0 & 2047;
#pragma unroll
    for (int i = 0; i < 4; i++) {
      int flat = i * 256 + t;     // 0..1023
      int dr = flat >> 4;         // 0..63 (local V col)
      int c8 = (flat & 15) * 8;   // 0..120 (local row)
      int col = wn0 + dr;
      if (col < 224) {
        int hh = col / 56, d = col - hh * 56;
        *(int4*)(Vt + ((size_t)((bb * 4 + hh) * 64 + d)) * 2048 + n_base + c8) =
            *(int4*)&TS(dr, c8);
      }
    }
  }
}

// ---------------------------------------------------------------------------
// Output projection: out = LNo (bf16) @ Wo^T. BM=128, BN=64, grid (32,14).
// Same dbuf + 3-deep prefetch structure.
// ---------------------------------------------------------------------------
__global__ __launch_bounds__(256) void gemm_wo(const u16* __restrict__ A,
                                               const u16* __restrict__ W,
                                               float* __restrict__ C) {
  __shared__ __align__(16) u16 As[2][128][68];
  __shared__ __align__(16) u16 Bs[2][64][68];
  const int t = threadIdx.x;
  const int m0 = blockIdx.x * 128;
  const int wn0 = blockIdx.y * 64;
  const int w = t >> 6, lane = t & 63;
  const int fr = lane & 15, fg = lane >> 4;
  const int wr = w * 32;

  f32x4 acc[2][4] = {};
  int4 a0[4], b0[2], a1[4], b1[2];

#define WO_LOAD(ar_, br_, k0_)                                                 \
  {                                                                            \
    _Pragma("unroll") for (int i = 0; i < 4; i++) {                            \
      int flat = i * 256 + t;                                                  \
      int r = flat >> 3, c = (flat & 7) * 8;                                   \
      ar_[i] = *(const int4*)(A + (size_t)(m0 + r) * EMBED + (k0_) + c);       \
    }                                                                          \
    _Pragma("unroll") for (int i = 0; i < 2; i++) {                            \
      int flat = i * 256 + t;                                                  \
      int r = flat >> 3, c = (flat & 7) * 8;                                   \
      br_[i] = *(const int4*)(W + (size_t)(wn0 + r) * EMBED + (k0_) + c);      \
    }                                                                          \
  }
#define WO_WRITE(buf_, ar_, br_)                                               \
  {                                                                            \
    _Pragma("unroll") for (int i = 0; i < 4; i++) {                            \
      int flat = i * 256 + t;                                                  \
      *(int4*)&As[buf_][flat >> 3][(flat & 7) * 8] = ar_[i];                   \
    }                                                                          \
    _Pragma("unroll") for (int i = 0; i < 2; i++) {                            \
      int flat = i * 256 + t;                                                  \
      *(int4*)&Bs[buf_][flat >> 3][(flat & 7) * 8] = br_[i];                   \
    }                                                                          \
  }
#define WO_COMPUTE(buf_)                                                       \
  {                                                                            \
    _Pragma("unroll") for (int kk = 0; kk < 2; kk++) {                         \
      bf16x8 af[2], bfv[4];                                                    \
      _Pragma("unroll") for (int mf = 0; mf < 2; mf++)                         \
          af[mf] =                                                             \
          *(const bf16x8*)&As[buf_][wr + mf * 16 + fr][kk * 32 + fg * 8];      \
      _Pragma("unroll") for (int nf = 0; nf < 4; nf++)                         \
          bfv[nf] = *(const bf16x8*)&Bs[buf_][nf * 16 + fr][kk * 32 + fg * 8]; \
      _Pragma("unroll") for (int mf = 0; mf < 2; mf++)                         \
          _Pragma("unroll") for (int nf = 0; nf < 4; nf++)                     \
              acc[mf][nf] = __builtin_amdgcn_mfma_f32_16x16x32_bf16(           \
                  af[mf], bfv[nf], acc[mf][nf], 0, 0, 0);                      \
    }                                                                          \
  }

  WO_LOAD(a0, b0, 0);
  WO_LOAD(a1, b1, 64);
  WO_WRITE(0, a0, b0);
  WO_LOAD(a0, b0, 128);
  __syncthreads();

#pragma unroll
  for (int it = 0; it < NT_K; it += 2) {
    WO_WRITE(1, a1, b1);
    if (it + 3 < NT_K) WO_LOAD(a1, b1, (it + 3) * 64);
    WO_COMPUTE(0);
    __syncthreads();
    if (it + 2 < NT_K) WO_WRITE(0, a0, b0);
    if (it + 4 < NT_K) WO_LOAD(a0, b0, (it + 4) * 64);
    WO_COMPUTE(1);
    __syncthreads();
  }

#pragma unroll
  for (int nf = 0; nf < 4; nf++) {
    int col = wn0 + nf * 16 + fr;
#pragma unroll
    for (int mf = 0; mf < 2; mf++)
#pragma unroll
      for (int r = 0; r < 4; r++) {
        int row = m0 + wr + mf * 16 + fg * 4 + r;
        C[(size_t)row * EMBED + col] = acc[mf][nf][r];
      }
  }
}

// ---------------------------------------------------------------------------
// Pass A: causal flash attention. Block = (strip-pair, hk, b); 4 waves, one
// head per wave sharing K/V LDS staging. 32-row q strips paired (s, 63-s).
// ---------------------------------------------------------------------------
__global__ __launch_bounds__(256) void attn_fwd(const u16* __restrict__ Qp,
                                                const u16* __restrict__ Kp,
                                                const u16* __restrict__ Vt,
                                                float* __restrict__ AO,
                                                float* __restrict__ linv_g) {
  const int p = blockIdx.x, hk = blockIdx.y, b = blockIdx.z;
  const int t = threadIdx.x, w = t >> 6, lane = t & 63;
  const int fr = lane & 15, fg = lane >> 4;
  const int h = hk * 4 + w;

  __shared__ __align__(16) u16 Ks[64][72];
  __shared__ __align__(16) u16 Vs[64][72];
  __shared__ __align__(16) u16 Ps[4][32][72];

  const u16* Qh = Qp + (size_t)(b * HQ + h) * N_ * DP;
  const u16* Kh = Kp + (size_t)(b * HK + hk) * N_ * DP;
  const u16* Vh = Vt + (size_t)(b * HK + hk) * DP * N_;
  float* linv_h = linv_g + (size_t)(b * HQ + h) * N_;

  const int f0 = t * 2, f1 = t * 2 + 1;

  for (int half = 0; half < 2; ++half) {
    const int s = half ? (63 - p) : p;
    const int nt = (s >> 1) + 1;

    bf16x8 qf[2][2];
#pragma unroll
    for (int m = 0; m < 2; m++)
#pragma unroll
      for (int kk = 0; kk < 2; kk++)
        qf[m][kk] = *(const bf16x8*)(Qh + (size_t)(s * 32 + m * 16 + fr) * DP +
                                     kk * 32 + fg * 8);

    f32x4 oacc[2][4] = {};
    float l_acc[2][4] = {};

    int4 kr0, kr1, vr0, vr1;
    {
      kr0 = *(const int4*)(Kh + f0 * 8);
      kr1 = *(const int4*)(Kh + f1 * 8);
      vr0 = *(const int4*)(Vh + (size_t)(f0 >> 3) * N_ + (f0 & 7) * 8);
      vr1 = *(const int4*)(Vh + (size_t)(f1 >> 3) * N_ + (f1 & 7) * 8);
    }

    for (int tt = 0; tt < nt; ++tt) {
      __syncthreads();
      *(int4*)&Ks[f0 >> 3][(f0 & 7) * 8] = kr0;
      *(int4*)&Ks[f1 >> 3][(f1 & 7) * 8] = kr1;
      *(int4*)&Vs[f0 >> 3][(f0 & 7) * 8] = vr0;
      *(int4*)&Vs[f1 >> 3][(f1 & 7) * 8] = vr1;
      __syncthreads();
      if (tt + 1 < nt) {
        const u16* Kb = Kh + (size_t)(tt + 1) * 64 * DP;
        kr0 = *(const int4*)(Kb + f0 * 8);
        kr1 = *(const int4*)(Kb + f1 * 8);
        const u16* Vb = Vh + (tt + 1) * 64;
        vr0 = *(const int4*)(Vb + (size_t)(f0 >> 3) * N_ + (f0 & 7) * 8);
        vr1 = *(const int4*)(Vb + (size_t)(f1 >> 3) * N_ + (f1 & 7) * 8);
      }

      f32x4 sacc[2][4] = {};
#pragma unroll
      for (int kk = 0; kk < 2; kk++) {
        bf16x8 bk[4];
#pragma unroll
        for (int jf = 0; jf < 4; jf++)
          bk[jf] = *(const bf16x8*)&Ks[jf * 16 + fr][kk * 32 + fg * 8];
#pragma unroll
        for (int m = 0; m < 2; m++)
#pragma unroll
          for (int jf = 0; jf < 4; jf++)
            sacc[m][jf] = __builtin_amdgcn_mfma_f32_16x16x32_bf16(
                qf[m][kk], bk[jf], sacc[m][jf], 0, 0, 0);
      }

      if (tt == nt - 1) {
#pragma unroll
        for (int m = 0; m < 2; m++)
#pragma unroll
          for (int jf = 0; jf < 4; jf++)
#pragma unroll
            for (int r = 0; r < 4; r++) {
              int gi = s * 32 + m * 16 + fg * 4 + r;
              int gj = tt * 64 + jf * 16 + fr;
              float pv = (gj <= gi) ? EXP2F(sacc[m][jf][r]) : 0.f;
              l_acc[m][r] += pv;
              Ps[w][m * 16 + fg * 4 + r][jf * 16 + fr] = f2bf(pv);
            }
      } else {
#pragma unroll
        for (int m = 0; m < 2; m++)
#pragma unroll
          for (int jf = 0; jf < 4; jf++)
#pragma unroll
            for (int r = 0; r < 4; r++) {
              float pv = EXP2F(sacc[m][jf][r]);
              l_acc[m][r] += pv;
              Ps[w][m * 16 + fg * 4 + r][jf * 16 + fr] = f2bf(pv);
            }
      }

#pragma unroll
      for (int kk = 0; kk < 2; kk++) {
        bf16x8 ap[2], bv[4];
#pragma unroll
        for (int m = 0; m < 2; m++)
          ap[m] = *(const bf16x8*)&Ps[w][m * 16 + fr][kk * 32 + fg * 8];
#pragma unroll
        for (int df = 0; df < 4; df++)
          bv[df] = *(const bf16x8*)&Vs[df * 16 + fr][kk * 32 + fg * 8];
#pragma unroll
        for (int m = 0; m < 2; m++)
#pragma unroll
          for (int df = 0; df < 4; df++)
            oacc[m][df] = __builtin_amdgcn_mfma_f32_16x16x32_bf16(
                ap[m], bv[df], oacc[m][df], 0, 0, 0);
      }
    }

#pragma unroll
    for (int m = 0; m < 2; m++)
#pragma unroll
      for (int r = 0; r < 4; r++) {
        float v = l_acc[m][r];
        v += __shfl_xor(v, 1);
        v += __shfl_xor(v, 2);
        v += __shfl_xor(v, 4);
        v += __shfl_xor(v, 8);
        l_acc[m][r] = 1.0f / v;
      }
#pragma unroll
    for (int m = 0; m < 2; m++)
#pragma unroll
      for (int df = 0; df < 4; df++) {
        int d = df * 16 + fr;
        if (d < D_) {
#pragma unroll
          for (int r = 0; r < 4; r++) {
            int gi = s * 32 + m * 16 + fg * 4 + r;
            AO[((size_t)b * N_ + gi) * EMBED + h * D_ + d] =
                oacc[m][df][r] * l_acc[m][r];
          }
        }
      }
    if (fr == 0) {
#pragma unroll
      for (int m = 0; m < 2; m++)
#pragma unroll
        for (int r = 0; r < 4; r++)
          linv_h[s * 32 + m * 16 + fg * 4 + r] = l_acc[m][r];
    }
  }
}

// ---------------------------------------------------------------------------
// Pass B: attention-weight column means via transposed scores T = K*Q^T.
// ---------------------------------------------------------------------------
struct QTile {
  bf16x8 q[4][2];
  float li[4];
};

#define LOADQ(dst, rt_)                                                        \
  {                                                                            \
    _Pragma("unroll") for (int ifr = 0; ifr < 4; ifr++) {                      \
      _Pragma("unroll") for (int kk = 0; kk < 2; kk++)                         \
          dst.q[ifr][kk] = *(const bf16x8*)(Qh +                               \
              (size_t)((rt_)*64 + ifr * 16 + fr) * DP + kk * 32 + fg * 8);     \
      dst.li[ifr] = linv_h[(rt_)*64 + ifr * 16 + fr];                          \
    }                                                                          \
  }

#define COMPUTET(src, rt_)                                                     \
  {                                                                            \
    f32x4 tacc[2][4] = {};                                                     \
    _Pragma("unroll") for (int kk = 0; kk < 2; kk++)                           \
        _Pragma("unroll") for (int jm = 0; jm < 2; jm++)                       \
        _Pragma("unroll") for (int ifr = 0; ifr < 4; ifr++)                    \
            tacc[jm][ifr] = __builtin_amdgcn_mfma_f32_16x16x32_bf16(           \
                kf[jm][kk], src.q[ifr][kk], tacc[jm][ifr], 0, 0, 0);           \
    if ((rt_) == rt0) {                                                        \
      _Pragma("unroll") for (int jm = 0; jm < 2; jm++)                         \
          _Pragma("unroll") for (int ifr = 0; ifr < 4; ifr++)                  \
          _Pragma("unroll") for (int r = 0; r < 4; r++) {                      \
        int gi = (rt_)*64 + ifr * 16 + fr;                                     \
        int gj = ct * 32 + jm * 16 + fg * 4 + r;                               \
        if (gi >= gj)                                                          \
          s_acc[jm][r] += EXP2F(tacc[jm][ifr][r]) * src.li[ifr];               \
      }                                                                        \
    } else {                                                                   \
      _Pragma("unroll") for (int jm = 0; jm < 2; jm++)                         \
          _Pragma("unroll") for (int ifr = 0; ifr < 4; ifr++)                  \
          _Pragma("unroll") for (int r = 0; r < 4; r++)                        \
              s_acc[jm][r] += EXP2F(tacc[jm][ifr][r]) * src.li[ifr];           \
    }                                                                          \
  }

__global__ __launch_bounds__(256) void attn_aw(const u16* __restrict__ Qp,
                                               const u16* __restrict__ Kp,
                                               const float* __restrict__ linv_g,
                                               float* __restrict__ aw) {
  const int p = blockIdx.x, hk = blockIdx.y, b = blockIdx.z;
  const int t = threadIdx.x, w = t >> 6, lane = t & 63;
  const int fr = lane & 15, fg = lane >> 4;
  const int h = hk * 4 + w;

  const u16* Qh = Qp + (size_t)(b * HQ + h) * N_ * DP;
  const u16* Kh = Kp + (size_t)(b * HK + hk) * N_ * DP;
  const float* linv_h = linv_g + (size_t)(b * HQ + h) * N_;

  for (int half = 0; half < 2; ++half) {
    const int ct = half ? (63 - p) : p;
    const int rt0 = ct >> 1;

    bf16x8 kf[2][2];
#pragma unroll
    for (int jm = 0; jm < 2; jm++)
#pragma unroll
      for (int kk = 0; kk < 2; kk++)
        kf[jm][kk] = *(const bf16x8*)(Kh + (size_t)(ct * 32 + jm * 16 + fr) * DP +
                                      kk * 32 + fg * 8);

    float s_acc[2][4] = {};
    QTile qa, qb;
    LOADQ(qa, rt0);
    int rt = rt0;
    while (true) {
      if (rt + 1 <= 31) LOADQ(qb, rt + 1);
      COMPUTET(qa, rt);
      rt++;
      if (rt > 31) break;
      if (rt + 1 <= 31) LOADQ(qa, rt + 1);
      COMPUTET(qb, rt);
      rt++;
      if (rt > 31) break;
    }

#pragma unroll
    for (int jm = 0; jm < 2; jm++)
#pragma unroll
      for (int r = 0; r < 4; r++) {
        float v = s_acc[jm][r];
        v += __shfl_xor(v, 1);
        v += __shfl_xor(v, 2);
        v += __shfl_xor(v, 4);
        v += __shfl_xor(v, 8);
        if (fr == 0) {
          int gj = ct * 32 + jm * 16 + fg * 4 + r;
          aw[((size_t)b * N_ + gj) * HQ + h] = v * (1.0f / N_);
        }
      }
  }
}

// ---------------------------------------------------------------------------
// LayerNorm over EMBED, one block per row; bf16 output for the Wo GEMM.
// ---------------------------------------------------------------------------
__global__ __launch_bounds__(256) void ln_fwd(const float* __restrict__ AO,
                                              const float* __restrict__ gamma,
                                              const float* __restrict__ beta,
                                              u16* __restrict__ out) {
  const int row = blockIdx.x;
  const float* x = AO + (size_t)row * EMBED;
  const int t = threadIdx.x;
  float s = 0.f, s2 = 0.f;
  float v[4];
#pragma unroll
  for (int i = 0; i < 4; i++) {
    int c = t + 256 * i;
    v[i] = (c < EMBED) ? x[c] : 0.f;
    s += v[i];
    s2 += v[i] * v[i];
  }
#pragma unroll
  for (int m = 1; m <= 32; m <<= 1) {
    s += __shfl_xor(s, m);
    s2 += __shfl_xor(s2, m);
  }
  __shared__ float red[8];
  const int w = t >> 6, lane = t & 63;
  if (lane == 0) {
    red[w] = s;
    red[4 + w] = s2;
  }
  __syncthreads();
  s = red[0] + red[1] + red[2] + red[3];
  s2 = red[4] + red[5] + red[6] + red[7];
  const float mu = s * (1.0f / EMBED);
  const float var = s2 * (1.0f / EMBED) - mu * mu;
  const float rs = rsqrtf(var + 1e-5f);
#pragma unroll
  for (int i = 0; i < 4; i++) {
    int c = t + 256 * i;
    if (c < EMBED)
      out[(size_t)row * EMBED + c] = f2bf((v[i] - mu) * rs * gamma[c] + beta[c]);
  }
}

// ---------------------------------------------------------------------------
extern "C" void kernel_launch(void* const* d_in, const int* in_sizes, int n_in,
                              void* d_out, int out_size, void* d_ws,
                              size_t ws_size, hipStream_t stream) {
  (void)in_sizes; (void)n_in; (void)out_size; (void)ws_size;
  const float* query = (const float*)d_in[0];
  const float* key   = (const float*)d_in[1];
  const float* value = (const float*)d_in[2];
  const float* Wq    = (const float*)d_in[3];
  const float* Wk    = (const float*)d_in[4];
  const float* Wv    = (const float*)d_in[5];
  const float* Wo    = (const float*)d_in[6];
  const float* gamma = (const float*)d_in[7];
  const float* beta  = (const float*)d_in[8];

  float* out = (float*)d_out;                   // (b, n, EMBED) f32
  float* aw  = out + (size_t)B_ * N_ * EMBED;   // (b, s, HQ)   f32

  char* ws = (char*)d_ws;
  u16* Qp = (u16*)ws;        ws += (size_t)B_ * HQ * N_ * DP * 2;   // 8.39 MB
  u16* Kp = (u16*)ws;        ws += (size_t)B_ * HK * N_ * DP * 2;   // 2.10 MB
  u16* Vt = (u16*)ws;        ws += (size_t)B_ * HK * N_ * DP * 2;   // 2.10 MB
  float* linv = (float*)ws;  ws += (size_t)B_ * HQ * N_ * 4;        // 0.26 MB
  u16* Wqb = (u16*)ws;       ws += (size_t)SEG_WQ * 2;              // 1.61 MB
  u16* Wkb = (u16*)ws;       ws += (size_t)SEG_WK * 2;              // 0.40 MB
  u16* Wvb = (u16*)ws;       ws += (size_t)SEG_WK * 2;              // 0.40 MB
  u16* Wob = (u16*)ws;       ws += (size_t)SEG_WQ * 2;              // 1.61 MB
  char* region = ws;         // 22.02 MB region, two lifetimes:
  u16* qb = (u16*)region;                        // phase 1: qb/kb/vb
  u16* kb = qb + (size_t)SEG_IN;
  u16* vb = kb + (size_t)SEG_IN;
  float* AO = (float*)region;                    // phase 2: AO + LNo
  u16* LNo = (u16*)(region + (size_t)B_ * N_ * EMBED * 4);

  const size_t pad_bytes =
      ((size_t)B_ * HQ * N_ * DP + 2 * (size_t)B_ * HK * N_ * DP) * 2;
  (void)hipMemsetAsync(Qp, 0, pad_bytes, stream);  // zero d=56..63 pads

  dim3 blk(256);
  const int M = B_ * N_;  // 4096

  to_bf16<<<dim3(12712), blk, 0, stream>>>(query, key, value, Wq, Wk, Wv, Wo,
                                           qb, kb, vb, Wqb, Wkb, Wvb, Wob);

  proj_gemm<<<dim3(M / 128, 22), blk, 0, stream>>>(qb, kb, vb, Wqb, Wkb, Wvb,
                                                   Qp, Kp, Vt);

  attn_fwd<<<dim3(32, HK, B_), blk, 0, stream>>>(Qp, Kp, Vt, AO, linv);
  attn_aw<<<dim3(32, HK, B_), blk, 0, stream>>>(Qp, Kp, linv, aw);

  ln_fwd<<<dim3(M), blk, 0, stream>>>(AO, gamma, beta, LNo);
  gemm_wo<<<dim3(M / 128, 14), blk, 0, stream>>>(LNo, Wob, out);
}

// Round 7
// 200.658 us; speedup vs baseline: 1.0326x; 1.0326x over previous
//
#include <hip/hip_runtime.h>

#define B_    2
#define N_    2048
#define EMBED 896
#define HQ    16
#define HK    4
#define D_    56
#define DP    64

typedef unsigned short u16;
typedef unsigned int   u32;
typedef __attribute__((ext_vector_type(8))) short bf16x8;
typedef __attribute__((ext_vector_type(4))) float f32x4;

__device__ __forceinline__ u16 f2bf(float f) {
  u32 u = __builtin_bit_cast(u32, f);
  return (u16)((u + 0x7FFFu + ((u >> 16) & 1u)) >> 16);
}

#define EXP2F(x) __builtin_amdgcn_exp2f(x)

// LDS-only barrier: waits DS ops, leaves global prefetch loads IN FLIGHT
// (hipcc's __syncthreads drains vmcnt(0) — the round-6 diagnosed stall).
__device__ __forceinline__ void lds_barrier() {
  asm volatile("s_waitcnt lgkmcnt(0)" ::: "memory");
  __builtin_amdgcn_s_barrier();
  asm volatile("" ::: "memory");
}

// QSCALE = (1/sqrt(56)) * log2(e); folded into Q so softmax uses exp2
#define QSCALE 0.19278822f

// ---------------------------------------------------------------------------
// Bulk f32 -> bf16 conversion of q/k/v inputs and the four weights.
// ---------------------------------------------------------------------------
#define SEG_IN  3670016u   // 2*2048*896
#define SEG_WQ  802816u    // 896*896
#define SEG_WK  200704u    // 224*896

__global__ __launch_bounds__(256) void to_bf16(
    const float* __restrict__ q, const float* __restrict__ k,
    const float* __restrict__ v, const float* __restrict__ wq,
    const float* __restrict__ wk, const float* __restrict__ wv,
    const float* __restrict__ wo, u16* __restrict__ qb, u16* __restrict__ kb,
    u16* __restrict__ vb, u16* __restrict__ wqb, u16* __restrict__ wkb,
    u16* __restrict__ wvb, u16* __restrict__ wob) {
  size_t e = ((size_t)blockIdx.x * 256 + threadIdx.x) * 4;
  const float* src;
  u16* dst;
  size_t off;
  if (e < SEG_IN)            { src = q;  dst = qb;  off = e; }
  else if (e < 2 * (size_t)SEG_IN) { src = k;  dst = kb;  off = e - SEG_IN; }
  else if (e < 3 * (size_t)SEG_IN) { src = v;  dst = vb;  off = e - 2 * (size_t)SEG_IN; }
  else {
    size_t r = e - 3 * (size_t)SEG_IN;
    if (r < SEG_WQ)                    { src = wq; dst = wqb; off = r; }
    else if (r < SEG_WQ + SEG_WK)      { src = wk; dst = wkb; off = r - SEG_WQ; }
    else if (r < SEG_WQ + 2 * SEG_WK)  { src = wv; dst = wvb; off = r - SEG_WQ - SEG_WK; }
    else                               { src = wo; dst = wob; off = r - SEG_WQ - 2 * SEG_WK; }
  }
  float4 v4 = *(const float4*)(src + off);
  uint2 pb;
  pb.x = (u32)f2bf(v4.x) | ((u32)f2bf(v4.y) << 16);
  pb.y = (u32)f2bf(v4.z) | ((u32)f2bf(v4.w) << 16);
  *(uint2*)(dst + off) = pb;
}

// ---------------------------------------------------------------------------
// Fused QKV projection GEMM. BM=128, BN=64, BK=64; grid (32, 22).
// Double-buffered LDS + 3-deep register prefetch + LDS-only barriers.
// ---------------------------------------------------------------------------
#define NT_K 14  // 896/64

__global__ __launch_bounds__(256) void proj_gemm(
    const u16* __restrict__ qb, const u16* __restrict__ kb,
    const u16* __restrict__ vb, const u16* __restrict__ Wqb,
    const u16* __restrict__ Wkb, const u16* __restrict__ Wvb,
    u16* __restrict__ Qp, u16* __restrict__ Kp, u16* __restrict__ Vt) {
  __shared__ __align__(16) u16 As[2][128][68];
  __shared__ __align__(16) u16 Bs[2][64][68];
  const int t = threadIdx.x;
  const int m0 = blockIdx.x * 128;
  const int y = blockIdx.y;
  int p, nt;
  if (y < 14)      { p = 0; nt = y; }
  else if (y < 18) { p = 1; nt = y - 14; }
  else             { p = 2; nt = y - 18; }
  const u16* A = p == 0 ? qb : (p == 1 ? kb : vb);
  const u16* W = p == 0 ? Wqb : (p == 1 ? Wkb : Wvb);
  const int Nproj = p == 0 ? 896 : 224;
  const int wn0 = nt * 64;

  const int w = t >> 6, lane = t & 63;
  const int fr = lane & 15, fg = lane >> 4;
  const int wr = w * 32;

  f32x4 acc[2][4] = {};
  int4 a0[4], b0[2], a1[4], b1[2];

#define PJ_LOAD(ar_, br_, k0_)                                                 \
  {                                                                            \
    _Pragma("unroll") for (int i = 0; i < 4; i++) {                            \
      int flat = i * 256 + t;                                                  \
      int r = flat >> 3, c = (flat & 7) * 8;                                   \
      ar_[i] = *(const int4*)(A + (size_t)(m0 + r) * EMBED + (k0_) + c);       \
    }                                                                          \
    _Pragma("unroll") for (int i = 0; i < 2; i++) {                            \
      int flat = i * 256 + t;                                                  \
      int r = flat >> 3, c = (flat & 7) * 8;                                   \
      int4 z = {0, 0, 0, 0};                                                   \
      if (wn0 + r < Nproj)                                                     \
        z = *(const int4*)(W + (size_t)(wn0 + r) * EMBED + (k0_) + c);         \
      br_[i] = z;                                                              \
    }                                                                          \
  }
#define PJ_WRITE(buf_, ar_, br_)                                               \
  {                                                                            \
    _Pragma("unroll") for (int i = 0; i < 4; i++) {                            \
      int flat = i * 256 + t;                                                  \
      *(int4*)&As[buf_][flat >> 3][(flat & 7) * 8] = ar_[i];                   \
    }                                                                          \
    _Pragma("unroll") for (int i = 0; i < 2; i++) {                            \
      int flat = i * 256 + t;                                                  \
      *(int4*)&Bs[buf_][flat >> 3][(flat & 7) * 8] = br_[i];                   \
    }                                                                          \
  }
#define PJ_COMPUTE(buf_)                                                       \
  {                                                                            \
    _Pragma("unroll") for (int kk = 0; kk < 2; kk++) {                         \
      bf16x8 af[2], bfv[4];                                                    \
      _Pragma("unroll") for (int mf = 0; mf < 2; mf++)                         \
          af[mf] =                                                             \
          *(const bf16x8*)&As[buf_][wr + mf * 16 + fr][kk * 32 + fg * 8];      \
      _Pragma("unroll") for (int nf = 0; nf < 4; nf++)                         \
          bfv[nf] = *(const bf16x8*)&Bs[buf_][nf * 16 + fr][kk * 32 + fg * 8]; \
      _Pragma("unroll") for (int mf = 0; mf < 2; mf++)                         \
          _Pragma("unroll") for (int nf = 0; nf < 4; nf++)                     \
              acc[mf][nf] = __builtin_amdgcn_mfma_f32_16x16x32_bf16(           \
                  af[mf], bfv[nf], acc[mf][nf], 0, 0, 0);                      \
    }                                                                          \
  }

  // prologue: tiles 0,1 -> regs; tile0 -> buf0; tile2 -> regs(set0)
  PJ_LOAD(a0, b0, 0);
  PJ_LOAD(a1, b1, 64);
  PJ_WRITE(0, a0, b0);
  PJ_LOAD(a0, b0, 128);
  lds_barrier();

#pragma unroll
  for (int it = 0; it < NT_K; it += 2) {
    // even step: compute tile it (buf0); stage tile it+1 (set1); issue it+3
    PJ_WRITE(1, a1, b1);
    if (it + 3 < NT_K) PJ_LOAD(a1, b1, (it + 3) * 64);
    PJ_COMPUTE(0);
    lds_barrier();
    // odd step: compute tile it+1 (buf1); stage tile it+2 (set0); issue it+4
    if (it + 2 < NT_K) PJ_WRITE(0, a0, b0);
    if (it + 4 < NT_K) PJ_LOAD(a0, b0, (it + 4) * 64);
    PJ_COMPUTE(1);
    lds_barrier();
  }

  if (p < 2) {
#pragma unroll
    for (int nf = 0; nf < 4; nf++) {
      int col = wn0 + nf * 16 + fr;
      if (col < Nproj) {
        int hh = col / 56, d = col - hh * 56;
#pragma unroll
        for (int mf = 0; mf < 2; mf++)
#pragma unroll
          for (int r = 0; r < 4; r++) {
            int row = m0 + wr + mf * 16 + fg * 4 + r;
            int bb = row >> 11, nn = row & 2047;
            float vv = acc[mf][nf][r];
            if (p == 0)
              Qp[((size_t)((bb * 16 + hh) * 2048 + nn)) * 64 + d] =
                  f2bf(vv * QSCALE);
            else
              Kp[((size_t)((bb * 4 + hh) * 2048 + nn)) * 64 + d] = f2bf(vv);
          }
      }
    }
  } else {
    // V: transpose through LDS, then coalesced 256B-contiguous stores
    u16* Traw = &As[0][0][0];  // reuse; need 64*136 = 8704 u16
#define TS(r_, c_) Traw[(r_)*136 + (c_)]
#pragma unroll
    for (int nf = 0; nf < 4; nf++)
#pragma unroll
      for (int mf = 0; mf < 2; mf++)
#pragma unroll
        for (int r = 0; r < 4; r++)
          TS(nf * 16 + fr, wr + mf * 16 + fg * 4 + r) = f2bf(acc[mf][nf][r]);
    lds_barrier();
    const int bb = m0 >> 11, n_base = m0 & 2047;
#pragma unroll
    for (int i = 0; i < 4; i++) {
      int flat = i * 256 + t;     // 0..1023
      int dr = flat >> 4;         // 0..63 (local V col)
      int c8 = (flat & 15) * 8;   // 0..120 (local row)
      int col = wn0 + dr;
      if (col < 224) {
        int hh = col / 56, d = col - hh * 56;
        *(int4*)(Vt + ((size_t)((bb * 4 + hh) * 64 + d)) * 2048 + n_base + c8) =
            *(int4*)&TS(dr, c8);
      }
    }
  }
}

// ---------------------------------------------------------------------------
// Output projection: out = LNo (bf16) @ Wo^T. BM=128, BN=64, grid (32,14).
// ---------------------------------------------------------------------------
__global__ __launch_bounds__(256) void gemm_wo(const u16* __restrict__ A,
                                               const u16* __restrict__ W,
                                               float* __restrict__ C) {
  __shared__ __align__(16) u16 As[2][128][68];
  __shared__ __align__(16) u16 Bs[2][64][68];
  const int t = threadIdx.x;
  const int m0 = blockIdx.x * 128;
  const int wn0 = blockIdx.y * 64;
  const int w = t >> 6, lane = t & 63;
  const int fr = lane & 15, fg = lane >> 4;
  const int wr = w * 32;

  f32x4 acc[2][4] = {};
  int4 a0[4], b0[2], a1[4], b1[2];

#define WO_LOAD(ar_, br_, k0_)                                                 \
  {                                                                            \
    _Pragma("unroll") for (int i = 0; i < 4; i++) {                            \
      int flat = i * 256 + t;                                                  \
      int r = flat >> 3, c = (flat & 7) * 8;                                   \
      ar_[i] = *(const int4*)(A + (size_t)(m0 + r) * EMBED + (k0_) + c);       \
    }                                                                          \
    _Pragma("unroll") for (int i = 0; i < 2; i++) {                            \
      int flat = i * 256 + t;                                                  \
      int r = flat >> 3, c = (flat & 7) * 8;                                   \
      br_[i] = *(const int4*)(W + (size_t)(wn0 + r) * EMBED + (k0_) + c);      \
    }                                                                          \
  }
#define WO_WRITE(buf_, ar_, br_)                                               \
  {                                                                            \
    _Pragma("unroll") for (int i = 0; i < 4; i++) {                            \
      int flat = i * 256 + t;                                                  \
      *(int4*)&As[buf_][flat >> 3][(flat & 7) * 8] = ar_[i];                   \
    }                                                                          \
    _Pragma("unroll") for (int i = 0; i < 2; i++) {                            \
      int flat = i * 256 + t;                                                  \
      *(int4*)&Bs[buf_][flat >> 3][(flat & 7) * 8] = br_[i];                   \
    }                                                                          \
  }
#define WO_COMPUTE(buf_)                                                       \
  {                                                                            \
    _Pragma("unroll") for (int kk = 0; kk < 2; kk++) {                         \
      bf16x8 af[2], bfv[4];                                                    \
      _Pragma("unroll") for (int mf = 0; mf < 2; mf++)                         \
          af[mf] =                                                             \
          *(const bf16x8*)&As[buf_][wr + mf * 16 + fr][kk * 32 + fg * 8];      \
      _Pragma("unroll") for (int nf = 0; nf < 4; nf++)                         \
          bfv[nf] = *(const bf16x8*)&Bs[buf_][nf * 16 + fr][kk * 32 + fg * 8]; \
      _Pragma("unroll") for (int mf = 0; mf < 2; mf++)                         \
          _Pragma("unroll") for (int nf = 0; nf < 4; nf++)                     \
              acc[mf][nf] = __builtin_amdgcn_mfma_f32_16x16x32_bf16(           \
                  af[mf], bfv[nf], acc[mf][nf], 0, 0, 0);                      \
    }                                                                          \
  }

  WO_LOAD(a0, b0, 0);
  WO_LOAD(a1, b1, 64);
  WO_WRITE(0, a0, b0);
  WO_LOAD(a0, b0, 128);
  lds_barrier();

#pragma unroll
  for (int it = 0; it < NT_K; it += 2) {
    WO_WRITE(1, a1, b1);
    if (it + 3 < NT_K) WO_LOAD(a1, b1, (it + 3) * 64);
    WO_COMPUTE(0);
    lds_barrier();
    if (it + 2 < NT_K) WO_WRITE(0, a0, b0);
    if (it + 4 < NT_K) WO_LOAD(a0, b0, (it + 4) * 64);
    WO_COMPUTE(1);
    lds_barrier();
  }

#pragma unroll
  for (int nf = 0; nf < 4; nf++) {
    int col = wn0 + nf * 16 + fr;
#pragma unroll
    for (int mf = 0; mf < 2; mf++)
#pragma unroll
      for (int r = 0; r < 4; r++) {
        int row = m0 + wr + mf * 16 + fg * 4 + r;
        C[(size_t)row * EMBED + col] = acc[mf][nf][r];
      }
  }
}

// ---------------------------------------------------------------------------
// Pass A: causal flash attention. Block = (strip-pair, hk, b); 4 waves, one
// head per wave sharing K/V LDS staging. 32-row q strips paired (s, 63-s).
// LDS-only barriers keep K/V register prefetch in flight.
// ---------------------------------------------------------------------------
__global__ __launch_bounds__(256) void attn_fwd(const u16* __restrict__ Qp,
                                                const u16* __restrict__ Kp,
                                                const u16* __restrict__ Vt,
                                                float* __restrict__ AO,
                                                float* __restrict__ linv_g) {
  const int p = blockIdx.x, hk = blockIdx.y, b = blockIdx.z;
  const int t = threadIdx.x, w = t >> 6, lane = t & 63;
  const int fr = lane & 15, fg = lane >> 4;
  const int h = hk * 4 + w;

  __shared__ __align__(16) u16 Ks[64][72];
  __shared__ __align__(16) u16 Vs[64][72];
  __shared__ __align__(16) u16 Ps[4][32][72];

  const u16* Qh = Qp + (size_t)(b * HQ + h) * N_ * DP;
  const u16* Kh = Kp + (size_t)(b * HK + hk) * N_ * DP;
  const u16* Vh = Vt + (size_t)(b * HK + hk) * DP * N_;
  float* linv_h = linv_g + (size_t)(b * HQ + h) * N_;

  const int f0 = t * 2, f1 = t * 2 + 1;

  for (int half = 0; half < 2; ++half) {
    const int s = half ? (63 - p) : p;
    const int nt = (s >> 1) + 1;

    bf16x8 qf[2][2];
#pragma unroll
    for (int m = 0; m < 2; m++)
#pragma unroll
      for (int kk = 0; kk < 2; kk++)
        qf[m][kk] = *(const bf16x8*)(Qh + (size_t)(s * 32 + m * 16 + fr) * DP +
                                     kk * 32 + fg * 8);

    f32x4 oacc[2][4] = {};
    float l_acc[2][4] = {};

    int4 kr0, kr1, vr0, vr1;
    {
      kr0 = *(const int4*)(Kh + f0 * 8);
      kr1 = *(const int4*)(Kh + f1 * 8);
      vr0 = *(const int4*)(Vh + (size_t)(f0 >> 3) * N_ + (f0 & 7) * 8);
      vr1 = *(const int4*)(Vh + (size_t)(f1 >> 3) * N_ + (f1 & 7) * 8);
    }

    for (int tt = 0; tt < nt; ++tt) {
      lds_barrier();  // all waves done reading previous K/V
      *(int4*)&Ks[f0 >> 3][(f0 & 7) * 8] = kr0;
      *(int4*)&Ks[f1 >> 3][(f1 & 7) * 8] = kr1;
      *(int4*)&Vs[f0 >> 3][(f0 & 7) * 8] = vr0;
      *(int4*)&Vs[f1 >> 3][(f1 & 7) * 8] = vr1;
      lds_barrier();  // writes visible
      if (tt + 1 < nt) {
        const u16* Kb = Kh + (size_t)(tt + 1) * 64 * DP;
        kr0 = *(const int4*)(Kb + f0 * 8);
        kr1 = *(const int4*)(Kb + f1 * 8);
        const u16* Vb = Vh + (tt + 1) * 64;
        vr0 = *(const int4*)(Vb + (size_t)(f0 >> 3) * N_ + (f0 & 7) * 8);
        vr1 = *(const int4*)(Vb + (size_t)(f1 >> 3) * N_ + (f1 & 7) * 8);
      }

      f32x4 sacc[2][4] = {};
#pragma unroll
      for (int kk = 0; kk < 2; kk++) {
        bf16x8 bk[4];
#pragma unroll
        for (int jf = 0; jf < 4; jf++)
          bk[jf] = *(const bf16x8*)&Ks[jf * 16 + fr][kk * 32 + fg * 8];
#pragma unroll
        for (int m = 0; m < 2; m++)
#pragma unroll
          for (int jf = 0; jf < 4; jf++)
            sacc[m][jf] = __builtin_amdgcn_mfma_f32_16x16x32_bf16(
                qf[m][kk], bk[jf], sacc[m][jf], 0, 0, 0);
      }

      if (tt == nt - 1) {
#pragma unroll
        for (int m = 0; m < 2; m++)
#pragma unroll
          for (int jf = 0; jf < 4; jf++)
#pragma unroll
            for (int r = 0; r < 4; r++) {
              int gi = s * 32 + m * 16 + fg * 4 + r;
              int gj = tt * 64 + jf * 16 + fr;
              float pv = (gj <= gi) ? EXP2F(sacc[m][jf][r]) : 0.f;
              l_acc[m][r] += pv;
              Ps[w][m * 16 + fg * 4 + r][jf * 16 + fr] = f2bf(pv);
            }
      } else {
#pragma unroll
        for (int m = 0; m < 2; m++)
#pragma unroll
          for (int jf = 0; jf < 4; jf++)
#pragma unroll
            for (int r = 0; r < 4; r++) {
              float pv = EXP2F(sacc[m][jf][r]);
              l_acc[m][r] += pv;
              Ps[w][m * 16 + fg * 4 + r][jf * 16 + fr] = f2bf(pv);
            }
      }

#pragma unroll
      for (int kk = 0; kk < 2; kk++) {
        bf16x8 ap[2], bv[4];
#pragma unroll
        for (int m = 0; m < 2; m++)
          ap[m] = *(const bf16x8*)&Ps[w][m * 16 + fr][kk * 32 + fg * 8];
#pragma unroll
        for (int df = 0; df < 4; df++)
          bv[df] = *(const bf16x8*)&Vs[df * 16 + fr][kk * 32 + fg * 8];
#pragma unroll
        for (int m = 0; m < 2; m++)
#pragma unroll
          for (int df = 0; df < 4; df++)
            oacc[m][df] = __builtin_amdgcn_mfma_f32_16x16x32_bf16(
                ap[m], bv[df], oacc[m][df], 0, 0, 0);
      }
    }

#pragma unroll
    for (int m = 0; m < 2; m++)
#pragma unroll
      for (int r = 0; r < 4; r++) {
        float v = l_acc[m][r];
        v += __shfl_xor(v, 1);
        v += __shfl_xor(v, 2);
        v += __shfl_xor(v, 4);
        v += __shfl_xor(v, 8);
        l_acc[m][r] = 1.0f / v;
      }
#pragma unroll
    for (int m = 0; m < 2; m++)
#pragma unroll
      for (int df = 0; df < 4; df++) {
        int d = df * 16 + fr;
        if (d < D_) {
#pragma unroll
          for (int r = 0; r < 4; r++) {
            int gi = s * 32 + m * 16 + fg * 4 + r;
            AO[((size_t)b * N_ + gi) * EMBED + h * D_ + d] =
                oacc[m][df][r] * l_acc[m][r];
          }
        }
      }
    if (fr == 0) {
#pragma unroll
      for (int m = 0; m < 2; m++)
#pragma unroll
        for (int r = 0; r < 4; r++)
          linv_h[s * 32 + m * 16 + fg * 4 + r] = l_acc[m][r];
    }
  }
}

// ---------------------------------------------------------------------------
// Pass B: attention-weight column means via transposed scores T = K*Q^T.
// ---------------------------------------------------------------------------
struct QTile {
  bf16x8 q[4][2];
  float li[4];
};

#define LOADQ(dst, rt_)                                                        \
  {                                                                            \
    _Pragma("unroll") for (int ifr = 0; ifr < 4; ifr++) {                      \
      _Pragma("unroll") for (int kk = 0; kk < 2; kk++)                         \
          dst.q[ifr][kk] = *(const bf16x8*)(Qh +                               \
              (size_t)((rt_)*64 + ifr * 16 + fr) * DP + kk * 32 + fg * 8);     \
      dst.li[ifr] = linv_h[(rt_)*64 + ifr * 16 + fr];                          \
    }                                                                          \
  }

#define COMPUTET(src, rt_)                                                     \
  {                                                                            \
    f32x4 tacc[2][4] = {};                                                     \
    _Pragma("unroll") for (int kk = 0; kk < 2; kk++)                           \
        _Pragma("unroll") for (int jm = 0; jm < 2; jm++)                       \
        _Pragma("unroll") for (int ifr = 0; ifr < 4; ifr++)                    \
            tacc[jm][ifr] = __builtin_amdgcn_mfma_f32_16x16x32_bf16(           \
                kf[jm][kk], src.q[ifr][kk], tacc[jm][ifr], 0, 0, 0);           \
    if ((rt_) == rt0) {                                                        \
      _Pragma("unroll") for (int jm = 0; jm < 2; jm++)                         \
          _Pragma("unroll") for (int ifr = 0; ifr < 4; ifr++)                  \
          _Pragma("unroll") for (int r = 0; r < 4; r++) {                      \
        int gi = (rt_)*64 + ifr * 16 + fr;                                     \
        int gj = ct * 32 + jm * 16 + fg * 4 + r;                               \
        if (gi >= gj)                                                          \
          s_acc[jm][r] += EXP2F(tacc[jm][ifr][r]) * src.li[ifr];               \
      }                                                                        \
    } else {                                                                   \
      _Pragma("unroll") for (int jm = 0; jm < 2; jm++)                         \
          _Pragma("unroll") for (int ifr = 0; ifr < 4; ifr++)                  \
          _Pragma("unroll") for (int r = 0; r < 4; r++)                        \
              s_acc[jm][r] += EXP2F(tacc[jm][ifr][r]) * src.li[ifr];           \
    }                                                                          \
  }

__global__ __launch_bounds__(256) void attn_aw(const u16* __restrict__ Qp,
                                               const u16* __restrict__ Kp,
                                               const float* __restrict__ linv_g,
                                               float* __restrict__ aw) {
  const int p = blockIdx.x, hk = blockIdx.y, b = blockIdx.z;
  const int t = threadIdx.x, w = t >> 6, lane = t & 63;
  const int fr = lane & 15, fg = lane >> 4;
  const int h = hk * 4 + w;

  const u16* Qh = Qp + (size_t)(b * HQ + h) * N_ * DP;
  const u16* Kh = Kp + (size_t)(b * HK + hk) * N_ * DP;
  const float* linv_h = linv_g + (size_t)(b * HQ + h) * N_;

  for (int half = 0; half < 2; ++half) {
    const int ct = half ? (63 - p) : p;
    const int rt0 = ct >> 1;

    bf16x8 kf[2][2];
#pragma unroll
    for (int jm = 0; jm < 2; jm++)
#pragma unroll
      for (int kk = 0; kk < 2; kk++)
        kf[jm][kk] = *(const bf16x8*)(Kh + (size_t)(ct * 32 + jm * 16 + fr) * DP +
                                      kk * 32 + fg * 8);

    float s_acc[2][4] = {};
    QTile qa, qb;
    LOADQ(qa, rt0);
    int rt = rt0;
    while (true) {
      if (rt + 1 <= 31) LOADQ(qb, rt + 1);
      COMPUTET(qa, rt);
      rt++;
      if (rt > 31) break;
      if (rt + 1 <= 31) LOADQ(qa, rt + 1);
      COMPUTET(qb, rt);
      rt++;
      if (rt > 31) break;
    }

#pragma unroll
    for (int jm = 0; jm < 2; jm++)
#pragma unroll
      for (int r = 0; r < 4; r++) {
        float v = s_acc[jm][r];
        v += __shfl_xor(v, 1);
        v += __shfl_xor(v, 2);
        v += __shfl_xor(v, 4);
        v += __shfl_xor(v, 8);
        if (fr == 0) {
          int gj = ct * 32 + jm * 16 + fg * 4 + r;
          aw[((size_t)b * N_ + gj) * HQ + h] = v * (1.0f / N_);
        }
      }
  }
}

// ---------------------------------------------------------------------------
// LayerNorm over EMBED, one block per row; bf16 output for the Wo GEMM.
// ---------------------------------------------------------------------------
__global__ __launch_bounds__(256) void ln_fwd(const float* __restrict__ AO,
                                              const float* __restrict__ gamma,
                                              const float* __restrict__ beta,
                                              u16* __restrict__ out) {
  const int row = blockIdx.x;
  const float* x = AO + (size_t)row * EMBED;
  const int t = threadIdx.x;
  float s = 0.f, s2 = 0.f;
  float v[4];
#pragma unroll
  for (int i = 0; i < 4; i++) {
    int c = t + 256 * i;
    v[i] = (c < EMBED) ? x[c] : 0.f;
    s += v[i];
    s2 += v[i] * v[i];
  }
#pragma unroll
  for (int m = 1; m <= 32; m <<= 1) {
    s += __shfl_xor(s, m);
    s2 += __shfl_xor(s2, m);
  }
  __shared__ float red[8];
  const int w = t >> 6, lane = t & 63;
  if (lane == 0) {
    red[w] = s;
    red[4 + w] = s2;
  }
  __syncthreads();
  s = red[0] + red[1] + red[2] + red[3];
  s2 = red[4] + red[5] + red[6] + red[7];
  const float mu = s * (1.0f / EMBED);
  const float var = s2 * (1.0f / EMBED) - mu * mu;
  const float rs = rsqrtf(var + 1e-5f);
#pragma unroll
  for (int i = 0; i < 4; i++) {
    int c = t + 256 * i;
    if (c < EMBED)
      out[(size_t)row * EMBED + c] = f2bf((v[i] - mu) * rs * gamma[c] + beta[c]);
  }
}

// ---------------------------------------------------------------------------
extern "C" void kernel_launch(void* const* d_in, const int* in_sizes, int n_in,
                              void* d_out, int out_size, void* d_ws,
                              size_t ws_size, hipStream_t stream) {
  (void)in_sizes; (void)n_in; (void)out_size; (void)ws_size;
  const float* query = (const float*)d_in[0];
  const float* key   = (const float*)d_in[1];
  const float* value = (const float*)d_in[2];
  const float* Wq    = (const float*)d_in[3];
  const float* Wk    = (const float*)d_in[4];
  const float* Wv    = (const float*)d_in[5];
  const float* Wo    = (const float*)d_in[6];
  const float* gamma = (const float*)d_in[7];
  const float* beta  = (const float*)d_in[8];

  float* out = (float*)d_out;                   // (b, n, EMBED) f32
  float* aw  = out + (size_t)B_ * N_ * EMBED;   // (b, s, HQ)   f32

  char* ws = (char*)d_ws;
  u16* Qp = (u16*)ws;        ws += (size_t)B_ * HQ * N_ * DP * 2;   // 8.39 MB
  u16* Kp = (u16*)ws;        ws += (size_t)B_ * HK * N_ * DP * 2;   // 2.10 MB
  u16* Vt = (u16*)ws;        ws += (size_t)B_ * HK * N_ * DP * 2;   // 2.10 MB
  float* linv = (float*)ws;  ws += (size_t)B_ * HQ * N_ * 4;        // 0.26 MB
  u16* Wqb = (u16*)ws;       ws += (size_t)SEG_WQ * 2;              // 1.61 MB
  u16* Wkb = (u16*)ws;       ws += (size_t)SEG_WK * 2;              // 0.40 MB
  u16* Wvb = (u16*)ws;       ws += (size_t)SEG_WK * 2;              // 0.40 MB
  u16* Wob = (u16*)ws;       ws += (size_t)SEG_WQ * 2;              // 1.61 MB
  char* region = ws;         // 22.02 MB region, two lifetimes:
  u16* qb = (u16*)region;                        // phase 1: qb/kb/vb
  u16* kb = qb + (size_t)SEG_IN;
  u16* vb = kb + (size_t)SEG_IN;
  float* AO = (float*)region;                    // phase 2: AO + LNo
  u16* LNo = (u16*)(region + (size_t)B_ * N_ * EMBED * 4);

  const size_t pad_bytes =
      ((size_t)B_ * HQ * N_ * DP + 2 * (size_t)B_ * HK * N_ * DP) * 2;
  (void)hipMemsetAsync(Qp, 0, pad_bytes, stream);  // zero d=56..63 pads

  dim3 blk(256);
  const int M = B_ * N_;  // 4096

  to_bf16<<<dim3(12712), blk, 0, stream>>>(query, key, value, Wq, Wk, Wv, Wo,
                                           qb, kb, vb, Wqb, Wkb, Wvb, Wob);

  proj_gemm<<<dim3(M / 128, 22), blk, 0, stream>>>(qb, kb, vb, Wqb, Wkb, Wvb,
                                                   Qp, Kp, Vt);

  attn_fwd<<<dim3(32, HK, B_), blk, 0, stream>>>(Qp, Kp, Vt, AO, linv);
  attn_aw<<<dim3(32, HK, B_), blk, 0, stream>>>(Qp, Kp, linv, aw);

  ln_fwd<<<dim3(M), blk, 0, stream>>>(AO, gamma, beta, LNo);
  gemm_wo<<<dim3(M / 128, 14), blk, 0, stream>>>(LNo, Wob, out);
}

// Round 8
// 144.932 us; speedup vs baseline: 1.4297x; 1.3845x over previous
//
#include <hip/hip_runtime.h>

#define B_    2
#define N_    2048
#define EMBED 896
#define HQ    16
#define HK    4
#define D_    56
#define DP    64

typedef unsigned short u16;
typedef unsigned int   u32;
typedef __attribute__((ext_vector_type(8))) short bf16x8;
typedef __attribute__((ext_vector_type(4))) float f32x4;

__device__ __forceinline__ u16 f2bf(float f) {
  u32 u = __builtin_bit_cast(u32, f);
  return (u16)((u + 0x7FFFu + ((u >> 16) & 1u)) >> 16);
}

#define EXP2F(x) __builtin_amdgcn_exp2f(x)

// Async global->LDS, 16B per lane. LDS dest is wave-uniform base + lane*16.
__device__ __forceinline__ void gload_lds16(const u16* g, u16* l) {
  __builtin_amdgcn_global_load_lds(
      (const __attribute__((address_space(1))) void*)g,
      (__attribute__((address_space(3))) void*)l, 16, 0, 0);
}

// LDS-only barrier (keeps global loads in flight) — used by attn_fwd.
__device__ __forceinline__ void lds_barrier() {
  asm volatile("s_waitcnt lgkmcnt(0)" ::: "memory");
  __builtin_amdgcn_s_barrier();
  asm volatile("" ::: "memory");
}

// QSCALE = (1/sqrt(56)) * log2(e); folded into Q so softmax uses exp2
#define QSCALE 0.19278822f

// ---------------------------------------------------------------------------
// Bulk f32 -> bf16 conversion of q/k/v inputs and the four weights.
// ---------------------------------------------------------------------------
#define SEG_IN  3670016u   // 2*2048*896
#define SEG_WQ  802816u    // 896*896
#define SEG_WK  200704u    // 224*896

__global__ __launch_bounds__(256) void to_bf16(
    const float* __restrict__ q, const float* __restrict__ k,
    const float* __restrict__ v, const float* __restrict__ wq,
    const float* __restrict__ wk, const float* __restrict__ wv,
    const float* __restrict__ wo, u16* __restrict__ qb, u16* __restrict__ kb,
    u16* __restrict__ vb, u16* __restrict__ wqb, u16* __restrict__ wkb,
    u16* __restrict__ wvb, u16* __restrict__ wob) {
  size_t e = ((size_t)blockIdx.x * 256 + threadIdx.x) * 4;
  const float* src;
  u16* dst;
  size_t off;
  if (e < SEG_IN)            { src = q;  dst = qb;  off = e; }
  else if (e < 2 * (size_t)SEG_IN) { src = k;  dst = kb;  off = e - SEG_IN; }
  else if (e < 3 * (size_t)SEG_IN) { src = v;  dst = vb;  off = e - 2 * (size_t)SEG_IN; }
  else {
    size_t r = e - 3 * (size_t)SEG_IN;
    if (r < SEG_WQ)                    { src = wq; dst = wqb; off = r; }
    else if (r < SEG_WQ + SEG_WK)      { src = wk; dst = wkb; off = r - SEG_WQ; }
    else if (r < SEG_WQ + 2 * SEG_WK)  { src = wv; dst = wvb; off = r - SEG_WQ - SEG_WK; }
    else                               { src = wo; dst = wob; off = r - SEG_WQ - 2 * SEG_WK; }
  }
  float4 v4 = *(const float4*)(src + off);
  uint2 pb;
  pb.x = (u32)f2bf(v4.x) | ((u32)f2bf(v4.y) << 16);
  pb.y = (u32)f2bf(v4.z) | ((u32)f2bf(v4.w) << 16);
  *(uint2*)(dst + off) = pb;
}

// ---------------------------------------------------------------------------
// GEMM core (m97 structure): BM=128, BN=64, BK=64, 256 thr. Single-buffer
// linear LDS staged via global_load_lds width=16 (no staging VGPRs -> no
// spills). XOR swizzle: physical 16B slot p = s ^ (row&7), applied on the
// per-lane GLOBAL source (LDS dest linear) and on the swizzled ds_read.
// ---------------------------------------------------------------------------
#define NT_K 14  // 896/64

#define GEMM_CORE(APTR, WPTR)                                                  \
  for (int it = 0; it < NT_K; ++it) {                                          \
    const int k0 = it * 64;                                                    \
    {                                                                          \
      const u16* Ag = (APTR) + (size_t)m0 * EMBED + k0;                        \
      _Pragma("unroll") for (int i = 0; i < 4; i++) {                          \
        int f = i * 256 + t;                                                   \
        int r = f >> 3, s = (f & 7) ^ (r & 7);                                 \
        gload_lds16(Ag + (size_t)r * EMBED + s * 8,                            \
                    AsL + (i * 256 + fwbase) * 8);                             \
      }                                                                        \
      const u16* Wg = (WPTR) + (size_t)wn0 * EMBED + k0;                       \
      _Pragma("unroll") for (int i = 0; i < 2; i++) {                          \
        int f = i * 256 + t;                                                   \
        int r = f >> 3, s = (f & 7) ^ (r & 7);                                 \
        gload_lds16(Wg + (size_t)r * EMBED + s * 8,                            \
                    BsL + (i * 256 + fwbase) * 8);                             \
      }                                                                        \
    }                                                                          \
    __syncthreads(); /* drains vmcnt -> staged data visible */                 \
    _Pragma("unroll") for (int kk = 0; kk < 2; kk++) {                         \
      bf16x8 af[2], bfv[4];                                                    \
      _Pragma("unroll") for (int mf = 0; mf < 2; mf++) {                       \
        int ra = wr + mf * 16 + fr;                                            \
        af[mf] =                                                               \
            *(const bf16x8*)&AsL[ra * 64 + ((fg + kk * 4) ^ (ra & 7)) * 8];    \
      }                                                                        \
      _Pragma("unroll") for (int nf = 0; nf < 4; nf++) {                       \
        int rb = nf * 16 + fr;                                                 \
        bfv[nf] =                                                              \
            *(const bf16x8*)&BsL[rb * 64 + ((fg + kk * 4) ^ (rb & 7)) * 8];    \
      }                                                                        \
      _Pragma("unroll") for (int mf = 0; mf < 2; mf++)                         \
          _Pragma("unroll") for (int nf = 0; nf < 4; nf++)                     \
              acc[mf][nf] = __builtin_amdgcn_mfma_f32_16x16x32_bf16(           \
                  af[mf], bfv[nf], acc[mf][nf], 0, 0, 0);                      \
    }                                                                          \
    __syncthreads(); /* all waves done reading before next overwrite */        \
  }

// Fused QKV projection. grid (32, 22): y<14 Q, y<18 K, else V.
// NOTE: K/V weight n-tiles (224 rows) overread up to row 255 — lands in the
// next ws buffer (allocated), results masked by col<Nproj in the epilogue.
__global__ __launch_bounds__(256) void proj_gemm(
    const u16* __restrict__ qb, const u16* __restrict__ kb,
    const u16* __restrict__ vb, const u16* __restrict__ Wqb,
    const u16* __restrict__ Wkb, const u16* __restrict__ Wvb,
    u16* __restrict__ Qp, u16* __restrict__ Kp, u16* __restrict__ Vt) {
  __shared__ __align__(16) u16 lds[12288];  // AsL 128x64 | BsL 64x64
  u16* AsL = lds;
  u16* BsL = lds + 8192;
  const int t = threadIdx.x;
  const int m0 = blockIdx.x * 128;
  const int y = blockIdx.y;
  int p, nt;
  if (y < 14)      { p = 0; nt = y; }
  else if (y < 18) { p = 1; nt = y - 14; }
  else             { p = 2; nt = y - 18; }
  const u16* A = p == 0 ? qb : (p == 1 ? kb : vb);
  const u16* W = p == 0 ? Wqb : (p == 1 ? Wkb : Wvb);
  const int Nproj = p == 0 ? 896 : 224;
  const int wn0 = nt * 64;

  const int w = t >> 6, lane = t & 63;
  const int fr = lane & 15, fg = lane >> 4;
  const int wr = w * 32;
  const int fwbase = t & 192;  // w*64, wave-uniform

  f32x4 acc[2][4] = {};

  GEMM_CORE(A, W)

  if (p < 2) {
#pragma unroll
    for (int nf = 0; nf < 4; nf++) {
      int col = wn0 + nf * 16 + fr;
      if (col < Nproj) {
        int hh = col / 56, d = col - hh * 56;
#pragma unroll
        for (int mf = 0; mf < 2; mf++)
#pragma unroll
          for (int r = 0; r < 4; r++) {
            int row = m0 + wr + mf * 16 + fg * 4 + r;
            int bb = row >> 11, nn = row & 2047;
            float vv = acc[mf][nf][r];
            if (p == 0)
              Qp[((size_t)((bb * 16 + hh) * 2048 + nn)) * 64 + d] =
                  f2bf(vv * QSCALE);
            else
              Kp[((size_t)((bb * 4 + hh) * 2048 + nn)) * 64 + d] = f2bf(vv);
          }
      }
    }
  } else {
    // V: transpose through LDS (reuse staging buffer), coalesced int4 stores
    u16* Traw = lds;  // need 64*136 = 8704 <= 12288
#define TS(r_, c_) Traw[(r_)*136 + (c_)]
#pragma unroll
    for (int nf = 0; nf < 4; nf++)
#pragma unroll
      for (int mf = 0; mf < 2; mf++)
#pragma unroll
        for (int r = 0; r < 4; r++)
          TS(nf * 16 + fr, wr + mf * 16 + fg * 4 + r) = f2bf(acc[mf][nf][r]);
    __syncthreads();
    const int bb = m0 >> 11, n_base = m0 & 2047;
#pragma unroll
    for (int i = 0; i < 4; i++) {
      int flat = i * 256 + t;     // 0..1023
      int dr = flat >> 4;         // 0..63 (local V col)
      int c8 = (flat & 15) * 8;   // 0..120 (local row)
      int col = wn0 + dr;
      if (col < 224) {
        int hh = col / 56, d = col - hh * 56;
        *(int4*)(Vt + ((size_t)((bb * 4 + hh) * 64 + d)) * 2048 + n_base + c8) =
            *(int4*)&TS(dr, c8);
      }
    }
  }
}

// Output projection: out = LNo (bf16) @ Wo^T. grid (32, 14).
__global__ __launch_bounds__(256) void gemm_wo(const u16* __restrict__ A,
                                               const u16* __restrict__ W,
                                               float* __restrict__ C) {
  __shared__ __align__(16) u16 lds[12288];
  u16* AsL = lds;
  u16* BsL = lds + 8192;
  const int t = threadIdx.x;
  const int m0 = blockIdx.x * 128;
  const int wn0 = blockIdx.y * 64;
  const int w = t >> 6, lane = t & 63;
  const int fr = lane & 15, fg = lane >> 4;
  const int wr = w * 32;
  const int fwbase = t & 192;

  f32x4 acc[2][4] = {};

  GEMM_CORE(A, W)

#pragma unroll
  for (int nf = 0; nf < 4; nf++) {
    int col = wn0 + nf * 16 + fr;
#pragma unroll
    for (int mf = 0; mf < 2; mf++)
#pragma unroll
      for (int r = 0; r < 4; r++) {
        int row = m0 + wr + mf * 16 + fg * 4 + r;
        C[(size_t)row * EMBED + col] = acc[mf][nf][r];
      }
  }
}

// ---------------------------------------------------------------------------
// Pass A: causal flash attention. Block = (strip-pair, hk, b); 4 waves, one
// head per wave sharing K/V LDS staging. 32-row q strips paired (s, 63-s).
// LDS-only barriers keep K/V register prefetch in flight.
// ---------------------------------------------------------------------------
__global__ __launch_bounds__(256) void attn_fwd(const u16* __restrict__ Qp,
                                                const u16* __restrict__ Kp,
                                                const u16* __restrict__ Vt,
                                                float* __restrict__ AO,
                                                float* __restrict__ linv_g) {
  const int p = blockIdx.x, hk = blockIdx.y, b = blockIdx.z;
  const int t = threadIdx.x, w = t >> 6, lane = t & 63;
  const int fr = lane & 15, fg = lane >> 4;
  const int h = hk * 4 + w;

  __shared__ __align__(16) u16 Ks[64][72];
  __shared__ __align__(16) u16 Vs[64][72];
  __shared__ __align__(16) u16 Ps[4][32][72];

  const u16* Qh = Qp + (size_t)(b * HQ + h) * N_ * DP;
  const u16* Kh = Kp + (size_t)(b * HK + hk) * N_ * DP;
  const u16* Vh = Vt + (size_t)(b * HK + hk) * DP * N_;
  float* linv_h = linv_g + (size_t)(b * HQ + h) * N_;

  const int f0 = t * 2, f1 = t * 2 + 1;

  for (int half = 0; half < 2; ++half) {
    const int s = half ? (63 - p) : p;
    const int nt = (s >> 1) + 1;

    bf16x8 qf[2][2];
#pragma unroll
    for (int m = 0; m < 2; m++)
#pragma unroll
      for (int kk = 0; kk < 2; kk++)
        qf[m][kk] = *(const bf16x8*)(Qh + (size_t)(s * 32 + m * 16 + fr) * DP +
                                     kk * 32 + fg * 8);

    f32x4 oacc[2][4] = {};
    float l_acc[2][4] = {};

    int4 kr0, kr1, vr0, vr1;
    {
      kr0 = *(const int4*)(Kh + f0 * 8);
      kr1 = *(const int4*)(Kh + f1 * 8);
      vr0 = *(const int4*)(Vh + (size_t)(f0 >> 3) * N_ + (f0 & 7) * 8);
      vr1 = *(const int4*)(Vh + (size_t)(f1 >> 3) * N_ + (f1 & 7) * 8);
    }

    for (int tt = 0; tt < nt; ++tt) {
      lds_barrier();  // all waves done reading previous K/V
      *(int4*)&Ks[f0 >> 3][(f0 & 7) * 8] = kr0;
      *(int4*)&Ks[f1 >> 3][(f1 & 7) * 8] = kr1;
      *(int4*)&Vs[f0 >> 3][(f0 & 7) * 8] = vr0;
      *(int4*)&Vs[f1 >> 3][(f1 & 7) * 8] = vr1;
      lds_barrier();  // writes visible
      if (tt + 1 < nt) {
        const u16* Kb = Kh + (size_t)(tt + 1) * 64 * DP;
        kr0 = *(const int4*)(Kb + f0 * 8);
        kr1 = *(const int4*)(Kb + f1 * 8);
        const u16* Vb = Vh + (tt + 1) * 64;
        vr0 = *(const int4*)(Vb + (size_t)(f0 >> 3) * N_ + (f0 & 7) * 8);
        vr1 = *(const int4*)(Vb + (size_t)(f1 >> 3) * N_ + (f1 & 7) * 8);
      }

      f32x4 sacc[2][4] = {};
#pragma unroll
      for (int kk = 0; kk < 2; kk++) {
        bf16x8 bk[4];
#pragma unroll
        for (int jf = 0; jf < 4; jf++)
          bk[jf] = *(const bf16x8*)&Ks[jf * 16 + fr][kk * 32 + fg * 8];
#pragma unroll
        for (int m = 0; m < 2; m++)
#pragma unroll
          for (int jf = 0; jf < 4; jf++)
            sacc[m][jf] = __builtin_amdgcn_mfma_f32_16x16x32_bf16(
                qf[m][kk], bk[jf], sacc[m][jf], 0, 0, 0);
      }

      if (tt == nt - 1) {
#pragma unroll
        for (int m = 0; m < 2; m++)
#pragma unroll
          for (int jf = 0; jf < 4; jf++)
#pragma unroll
            for (int r = 0; r < 4; r++) {
              int gi = s * 32 + m * 16 + fg * 4 + r;
              int gj = tt * 64 + jf * 16 + fr;
              float pv = (gj <= gi) ? EXP2F(sacc[m][jf][r]) : 0.f;
              l_acc[m][r] += pv;
              Ps[w][m * 16 + fg * 4 + r][jf * 16 + fr] = f2bf(pv);
            }
      } else {
#pragma unroll
        for (int m = 0; m < 2; m++)
#pragma unroll
          for (int jf = 0; jf < 4; jf++)
#pragma unroll
            for (int r = 0; r < 4; r++) {
              float pv = EXP2F(sacc[m][jf][r]);
              l_acc[m][r] += pv;
              Ps[w][m * 16 + fg * 4 + r][jf * 16 + fr] = f2bf(pv);
            }
      }

#pragma unroll
      for (int kk = 0; kk < 2; kk++) {
        bf16x8 ap[2], bv[4];
#pragma unroll
        for (int m = 0; m < 2; m++)
          ap[m] = *(const bf16x8*)&Ps[w][m * 16 + fr][kk * 32 + fg * 8];
#pragma unroll
        for (int df = 0; df < 4; df++)
          bv[df] = *(const bf16x8*)&Vs[df * 16 + fr][kk * 32 + fg * 8];
#pragma unroll
        for (int m = 0; m < 2; m++)
#pragma unroll
          for (int df = 0; df < 4; df++)
            oacc[m][df] = __builtin_amdgcn_mfma_f32_16x16x32_bf16(
                ap[m], bv[df], oacc[m][df], 0, 0, 0);
      }
    }

#pragma unroll
    for (int m = 0; m < 2; m++)
#pragma unroll
      for (int r = 0; r < 4; r++) {
        float v = l_acc[m][r];
        v += __shfl_xor(v, 1);
        v += __shfl_xor(v, 2);
        v += __shfl_xor(v, 4);
        v += __shfl_xor(v, 8);
        l_acc[m][r] = 1.0f / v;
      }
#pragma unroll
    for (int m = 0; m < 2; m++)
#pragma unroll
      for (int df = 0; df < 4; df++) {
        int d = df * 16 + fr;
        if (d < D_) {
#pragma unroll
          for (int r = 0; r < 4; r++) {
            int gi = s * 32 + m * 16 + fg * 4 + r;
            AO[((size_t)b * N_ + gi) * EMBED + h * D_ + d] =
                oacc[m][df][r] * l_acc[m][r];
          }
        }
      }
    if (fr == 0) {
#pragma unroll
      for (int m = 0; m < 2; m++)
#pragma unroll
        for (int r = 0; r < 4; r++)
          linv_h[s * 32 + m * 16 + fg * 4 + r] = l_acc[m][r];
    }
  }
}

// ---------------------------------------------------------------------------
// Pass B: attention-weight column means via transposed scores T = K*Q^T.
// ---------------------------------------------------------------------------
struct QTile {
  bf16x8 q[4][2];
  float li[4];
};

#define LOADQ(dst, rt_)                                                        \
  {                                                                            \
    _Pragma("unroll") for (int ifr = 0; ifr < 4; ifr++) {                      \
      _Pragma("unroll") for (int kk = 0; kk < 2; kk++)                         \
          dst.q[ifr][kk] = *(const bf16x8*)(Qh +                               \
              (size_t)((rt_)*64 + ifr * 16 + fr) * DP + kk * 32 + fg * 8);     \
      dst.li[ifr] = linv_h[(rt_)*64 + ifr * 16 + fr];                          \
    }                                                                          \
  }

#define COMPUTET(src, rt_)                                                     \
  {                                                                            \
    f32x4 tacc[2][4] = {};                                                     \
    _Pragma("unroll") for (int kk = 0; kk < 2; kk++)                           \
        _Pragma("unroll") for (int jm = 0; jm < 2; jm++)                       \
        _Pragma("unroll") for (int ifr = 0; ifr < 4; ifr++)                    \
            tacc[jm][ifr] = __builtin_amdgcn_mfma_f32_16x16x32_bf16(           \
                kf[jm][kk], src.q[ifr][kk], tacc[jm][ifr], 0, 0, 0);           \
    if ((rt_) == rt0) {                                                        \
      _Pragma("unroll") for (int jm = 0; jm < 2; jm++)                         \
          _Pragma("unroll") for (int ifr = 0; ifr < 4; ifr++)                  \
          _Pragma("unroll") for (int r = 0; r < 4; r++) {                      \
        int gi = (rt_)*64 + ifr * 16 + fr;                                     \
        int gj = ct * 32 + jm * 16 + fg * 4 + r;                               \
        if (gi >= gj)                                                          \
          s_acc[jm][r] += EXP2F(tacc[jm][ifr][r]) * src.li[ifr];               \
      }                                                                        \
    } else {                                                                   \
      _Pragma("unroll") for (int jm = 0; jm < 2; jm++)                         \
          _Pragma("unroll") for (int ifr = 0; ifr < 4; ifr++)                  \
          _Pragma("unroll") for (int r = 0; r < 4; r++)                        \
              s_acc[jm][r] += EXP2F(tacc[jm][ifr][r]) * src.li[ifr];           \
    }                                                                          \
  }

__global__ __launch_bounds__(256) void attn_aw(const u16* __restrict__ Qp,
                                               const u16* __restrict__ Kp,
                                               const float* __restrict__ linv_g,
                                               float* __restrict__ aw) {
  const int p = blockIdx.x, hk = blockIdx.y, b = blockIdx.z;
  const int t = threadIdx.x, w = t >> 6, lane = t & 63;
  const int fr = lane & 15, fg = lane >> 4;
  const int h = hk * 4 + w;

  const u16* Qh = Qp + (size_t)(b * HQ + h) * N_ * DP;
  const u16* Kh = Kp + (size_t)(b * HK + hk) * N_ * DP;
  const float* linv_h = linv_g + (size_t)(b * HQ + h) * N_;

  for (int half = 0; half < 2; ++half) {
    const int ct = half ? (63 - p) : p;
    const int rt0 = ct >> 1;

    bf16x8 kf[2][2];
#pragma unroll
    for (int jm = 0; jm < 2; jm++)
#pragma unroll
      for (int kk = 0; kk < 2; kk++)
        kf[jm][kk] = *(const bf16x8*)(Kh + (size_t)(ct * 32 + jm * 16 + fr) * DP +
                                      kk * 32 + fg * 8);

    float s_acc[2][4] = {};
    QTile qa, qb;
    LOADQ(qa, rt0);
    int rt = rt0;
    while (true) {
      if (rt + 1 <= 31) LOADQ(qb, rt + 1);
      COMPUTET(qa, rt);
      rt++;
      if (rt > 31) break;
      if (rt + 1 <= 31) LOADQ(qa, rt + 1);
      COMPUTET(qb, rt);
      rt++;
      if (rt > 31) break;
    }

#pragma unroll
    for (int jm = 0; jm < 2; jm++)
#pragma unroll
      for (int r = 0; r < 4; r++) {
        float v = s_acc[jm][r];
        v += __shfl_xor(v, 1);
        v += __shfl_xor(v, 2);
        v += __shfl_xor(v, 4);
        v += __shfl_xor(v, 8);
        if (fr == 0) {
          int gj = ct * 32 + jm * 16 + fg * 4 + r;
          aw[((size_t)b * N_ + gj) * HQ + h] = v * (1.0f / N_);
        }
      }
  }
}

// ---------------------------------------------------------------------------
// LayerNorm over EMBED, one block per row; bf16 output for the Wo GEMM.
// ---------------------------------------------------------------------------
__global__ __launch_bounds__(256) void ln_fwd(const float* __restrict__ AO,
                                              const float* __restrict__ gamma,
                                              const float* __restrict__ beta,
                                              u16* __restrict__ out) {
  const int row = blockIdx.x;
  const float* x = AO + (size_t)row * EMBED;
  const int t = threadIdx.x;
  float s = 0.f, s2 = 0.f;
  float v[4];
#pragma unroll
  for (int i = 0; i < 4; i++) {
    int c = t + 256 * i;
    v[i] = (c < EMBED) ? x[c] : 0.f;
    s += v[i];
    s2 += v[i] * v[i];
  }
#pragma unroll
  for (int m = 1; m <= 32; m <<= 1) {
    s += __shfl_xor(s, m);
    s2 += __shfl_xor(s2, m);
  }
  __shared__ float red[8];
  const int w = t >> 6, lane = t & 63;
  if (lane == 0) {
    red[w] = s;
    red[4 + w] = s2;
  }
  __syncthreads();
  s = red[0] + red[1] + red[2] + red[3];
  s2 = red[4] + red[5] + red[6] + red[7];
  const float mu = s * (1.0f / EMBED);
  const float var = s2 * (1.0f / EMBED) - mu * mu;
  const float rs = rsqrtf(var + 1e-5f);
#pragma unroll
  for (int i = 0; i < 4; i++) {
    int c = t + 256 * i;
    if (c < EMBED)
      out[(size_t)row * EMBED + c] = f2bf((v[i] - mu) * rs * gamma[c] + beta[c]);
  }
}

// ---------------------------------------------------------------------------
extern "C" void kernel_launch(void* const* d_in, const int* in_sizes, int n_in,
                              void* d_out, int out_size, void* d_ws,
                              size_t ws_size, hipStream_t stream) {
  (void)in_sizes; (void)n_in; (void)out_size; (void)ws_size;
  const float* query = (const float*)d_in[0];
  const float* key   = (const float*)d_in[1];
  const float* value = (const float*)d_in[2];
  const float* Wq    = (const float*)d_in[3];
  const float* Wk    = (const float*)d_in[4];
  const float* Wv    = (const float*)d_in[5];
  const float* Wo    = (const float*)d_in[6];
  const float* gamma = (const float*)d_in[7];
  const float* beta  = (const float*)d_in[8];

  float* out = (float*)d_out;                   // (b, n, EMBED) f32
  float* aw  = out + (size_t)B_ * N_ * EMBED;   // (b, s, HQ)   f32

  char* ws = (char*)d_ws;
  u16* Qp = (u16*)ws;        ws += (size_t)B_ * HQ * N_ * DP * 2;   // 8.39 MB
  u16* Kp = (u16*)ws;        ws += (size_t)B_ * HK * N_ * DP * 2;   // 2.10 MB
  u16* Vt = (u16*)ws;        ws += (size_t)B_ * HK * N_ * DP * 2;   // 2.10 MB
  float* linv = (float*)ws;  ws += (size_t)B_ * HQ * N_ * 4;        // 0.26 MB
  u16* Wqb = (u16*)ws;       ws += (size_t)SEG_WQ * 2;              // 1.61 MB
  u16* Wkb = (u16*)ws;       ws += (size_t)SEG_WK * 2;              // 0.40 MB
  u16* Wvb = (u16*)ws;       ws += (size_t)SEG_WK * 2;              // 0.40 MB
  u16* Wob = (u16*)ws;       ws += (size_t)SEG_WQ * 2;              // 1.61 MB
  char* region = ws;         // 22.02 MB region, two lifetimes:
  u16* qb = (u16*)region;                        // phase 1: qb/kb/vb
  u16* kb = qb + (size_t)SEG_IN;
  u16* vb = kb + (size_t)SEG_IN;
  float* AO = (float*)region;                    // phase 2: AO + LNo
  u16* LNo = (u16*)(region + (size_t)B_ * N_ * EMBED * 4);

  const size_t pad_bytes =
      ((size_t)B_ * HQ * N_ * DP + 2 * (size_t)B_ * HK * N_ * DP) * 2;
  (void)hipMemsetAsync(Qp, 0, pad_bytes, stream);  // zero d=56..63 pads

  dim3 blk(256);
  const int M = B_ * N_;  // 4096

  to_bf16<<<dim3(12712), blk, 0, stream>>>(query, key, value, Wq, Wk, Wv, Wo,
                                           qb, kb, vb, Wqb, Wkb, Wvb, Wob);

  proj_gemm<<<dim3(M / 128, 22), blk, 0, stream>>>(qb, kb, vb, Wqb, Wkb, Wvb,
                                                   Qp, Kp, Vt);

  attn_fwd<<<dim3(32, HK, B_), blk, 0, stream>>>(Qp, Kp, Vt, AO, linv);
  attn_aw<<<dim3(32, HK, B_), blk, 0, stream>>>(Qp, Kp, linv, aw);

  ln_fwd<<<dim3(M), blk, 0, stream>>>(AO, gamma, beta, LNo);
  gemm_wo<<<dim3(M / 128, 14), blk, 0, stream>>>(LNo, Wob, out);
}